// Round 5
// baseline (117.354 us; speedup 1.0000x reference)
//
#include <hip/hip_runtime.h>
#include <math.h>

#ifndef NSWEEP
#define NSWEEP 4   // 4x4 SPD cyclic Jacobi: rel off-diag ~1e-8 after 4 sweeps
#endif

#define EPSV 1e-8f
#define NM 3        // matrices per thread (3*26=78 state VGPRs, <=128 total)
#define BT 256      // threads per block
#define MPB (NM * BT)

__device__ __forceinline__ float fast_rsqf(float x) {
#if __has_builtin(__builtin_amdgcn_rsqf)
  return __builtin_amdgcn_rsqf(x);
#else
  return rsqrtf(x);
#endif
}
__device__ __forceinline__ float fast_logf(float x) {
#if __has_builtin(__builtin_amdgcn_logf)
  return __builtin_amdgcn_logf(x) * 0.6931471805599453f;  // v_log_f32 is log2
#else
  return logf(x);
#endif
}

// Givens rotation (p,q), short-critical-path form (2 dependent rsq, no sqrt/rcp):
//   h = 1/r, p = |d|/r = cos(2T), q = 2+2p, ri = 1/sqrt(q)
//   c = sqrt((1+p)/2) = q*ri/2 ; s = sgn(d)*2a/r * ri ; t = tanT = 2n/q = 2n*ri^2
// Degenerate d=a=0: max(r2,1e-30) keeps h finite; cndmask sets p=1 -> c=1,s=0,t=0.
// Identical rotation convention to the verified R1 kernel (s,t carry sgn(d)).
#define JROT(APP, AQQ, APQ, AK1P, AK1Q, AK2P, AK2Q,                         \
             VP0, VQ0, VP1, VQ1, VP2, VQ2, VP3, VQ3)                        \
  do {                                                                      \
    float aa_ = APQ;                                                        \
    float d_ = AQQ - APP;                                                   \
    float a2_ = aa_ + aa_;                                                  \
    float r2_ = fmaf(d_, d_, a2_ * a2_);                                    \
    float h_ = fast_rsqf(fmaxf(r2_, 1e-30f));                               \
    float p_ = fabsf(d_) * h_;                                              \
    p_ = (r2_ <= 1e-30f) ? 1.0f : p_;                                       \
    float q_ = fmaf(2.0f, p_, 2.0f);                                        \
    float ri_ = fast_rsqf(q_);                                              \
    float c_ = q_ * (0.5f * ri_);                                           \
    float n_ = __int_as_float(__float_as_int(a2_ * h_) ^                    \
                              (__float_as_int(d_) & 0x80000000));           \
    float s_ = n_ * ri_;                                                    \
    float t_ = (n_ + n_) * (ri_ * ri_);                                     \
    float ta_ = t_ * aa_;                                                   \
    APP = APP - ta_;                                                        \
    AQQ = AQQ + ta_;                                                        \
    APQ = 0.0f;                                                             \
    { float kp_ = AK1P, kq_ = AK1Q;                                         \
      AK1P = fmaf(c_, kp_, -s_ * kq_);                                      \
      AK1Q = fmaf(s_, kp_, c_ * kq_); }                                     \
    { float kp_ = AK2P, kq_ = AK2Q;                                         \
      AK2P = fmaf(c_, kp_, -s_ * kq_);                                      \
      AK2Q = fmaf(s_, kp_, c_ * kq_); }                                     \
    { float p0_ = VP0, q0_ = VQ0;                                           \
      VP0 = fmaf(c_, p0_, -s_ * q0_);                                       \
      VQ0 = fmaf(s_, p0_, c_ * q0_); }                                      \
    { float p0_ = VP1, q0_ = VQ1;                                           \
      VP1 = fmaf(c_, p0_, -s_ * q0_);                                       \
      VQ1 = fmaf(s_, p0_, c_ * q0_); }                                      \
    { float p0_ = VP2, q0_ = VQ2;                                           \
      VP2 = fmaf(c_, p0_, -s_ * q0_);                                       \
      VQ2 = fmaf(s_, p0_, c_ * q0_); }                                      \
    { float p0_ = VP3, q0_ = VQ3;                                           \
      VP3 = fmaf(c_, p0_, -s_ * q0_);                                       \
      VQ3 = fmaf(s_, p0_, c_ * q0_); }                                      \
  } while (0)

// Rotation at position (P,Q) for matrix m. A upper-tri idx: (0,0)=0 (0,1)=1
// (0,2)=2 (0,3)=3 (1,1)=4 (1,2)=5 (1,3)=6 (2,2)=7 (2,3)=8 (3,3)=9.
// V[m][i*4+j] = V_ij. All indices compile-time after unroll -> registers.
#define ROT_01(m) JROT(A[m][0], A[m][4], A[m][1], A[m][2], A[m][5],         \
                       A[m][3], A[m][6], V[m][0], V[m][1], V[m][4],         \
                       V[m][5], V[m][8], V[m][9], V[m][12], V[m][13])
#define ROT_02(m) JROT(A[m][0], A[m][7], A[m][2], A[m][1], A[m][5],         \
                       A[m][3], A[m][8], V[m][0], V[m][2], V[m][4],         \
                       V[m][6], V[m][8], V[m][10], V[m][12], V[m][14])
#define ROT_03(m) JROT(A[m][0], A[m][9], A[m][3], A[m][1], A[m][6],         \
                       A[m][2], A[m][8], V[m][0], V[m][3], V[m][4],         \
                       V[m][7], V[m][8], V[m][11], V[m][12], V[m][15])
#define ROT_12(m) JROT(A[m][4], A[m][7], A[m][5], A[m][1], A[m][2],         \
                       A[m][6], A[m][8], V[m][1], V[m][2], V[m][5],         \
                       V[m][6], V[m][9], V[m][10], V[m][13], V[m][14])
#define ROT_13(m) JROT(A[m][4], A[m][9], A[m][6], A[m][1], A[m][3],         \
                       A[m][5], A[m][8], V[m][1], V[m][3], V[m][5],         \
                       V[m][7], V[m][9], V[m][11], V[m][13], V[m][15])
#define ROT_23(m) JROT(A[m][7], A[m][9], A[m][8], A[m][2], A[m][3],         \
                       A[m][5], A[m][6], V[m][2], V[m][3], V[m][6],         \
                       V[m][7], V[m][10], V[m][11], V[m][14], V[m][15])

__global__ __launch_bounds__(256) void TangentSpaceLayer_64141041598486_kernel(
    const float* __restrict__ x, float* __restrict__ out, int B) {
  __shared__ __align__(16) float so[MPB * 10];
  const int t = threadIdx.x;
  const int base = blockIdx.x * MPB;

  float A[NM][10];
  float V[NM][16];

#pragma unroll
  for (int m = 0; m < NM; ++m) {
    const int idx = min(base + m * BT + t, B - 1);  // clamped tail, discarded
    const float4* p = (const float4*)(x + (size_t)idx * 16);
    float4 r0 = p[0], r1 = p[1], r2 = p[2], r3 = p[3];
    A[m][0] = r0.x + EPSV;
    A[m][1] = 0.5f * (r0.y + r1.x);
    A[m][2] = 0.5f * (r0.z + r2.x);
    A[m][3] = 0.5f * (r0.w + r3.x);
    A[m][4] = r1.y + EPSV;
    A[m][5] = 0.5f * (r1.z + r2.y);
    A[m][6] = 0.5f * (r1.w + r3.y);
    A[m][7] = r2.z + EPSV;
    A[m][8] = 0.5f * (r2.w + r3.z);
    A[m][9] = r3.w + EPSV;
#pragma unroll
    for (int i = 0; i < 16; ++i) V[m][i] = (i % 5 == 0) ? 1.0f : 0.0f;
  }

#pragma unroll 1
  for (int sweep = 0; sweep < NSWEEP; ++sweep) {
    // 3 independent chains interleaved per rotation position (latency hiding)
#pragma unroll
    for (int m = 0; m < NM; ++m) ROT_01(m);
#pragma unroll
    for (int m = 0; m < NM; ++m) ROT_02(m);
#pragma unroll
    for (int m = 0; m < NM; ++m) ROT_03(m);
#pragma unroll
    for (int m = 0; m < NM; ++m) ROT_12(m);
#pragma unroll
    for (int m = 0; m < NM; ++m) ROT_13(m);
#pragma unroll
    for (int m = 0; m < NM; ++m) ROT_23(m);
  }

#pragma unroll
  for (int m = 0; m < NM; ++m) {
    float lw0 = fast_logf(fmaxf(A[m][0], EPSV));
    float lw1 = fast_logf(fmaxf(A[m][4], EPSV));
    float lw2 = fast_logf(fmaxf(A[m][7], EPSV));
    float lw3 = fast_logf(fmaxf(A[m][9], EPSV));

    float w00 = V[m][0] * lw0, w01 = V[m][1] * lw1, w02 = V[m][2] * lw2,
          w03 = V[m][3] * lw3;
    float w10 = V[m][4] * lw0, w11 = V[m][5] * lw1, w12 = V[m][6] * lw2,
          w13 = V[m][7] * lw3;
    float w20 = V[m][8] * lw0, w21 = V[m][9] * lw1, w22 = V[m][10] * lw2,
          w23 = V[m][11] * lw3;
    float w30 = V[m][12] * lw0, w31 = V[m][13] * lw1, w32 = V[m][14] * lw2,
          w33 = V[m][15] * lw3;

    float* sp = so + (m * BT + t) * 10;
    sp[0] = fmaf(w00, V[m][0], fmaf(w01, V[m][1], fmaf(w02, V[m][2], w03 * V[m][3])));
    sp[1] = fmaf(w00, V[m][4], fmaf(w01, V[m][5], fmaf(w02, V[m][6], w03 * V[m][7])));
    sp[2] = fmaf(w00, V[m][8], fmaf(w01, V[m][9], fmaf(w02, V[m][10], w03 * V[m][11])));
    sp[3] = fmaf(w00, V[m][12], fmaf(w01, V[m][13], fmaf(w02, V[m][14], w03 * V[m][15])));
    sp[4] = fmaf(w10, V[m][4], fmaf(w11, V[m][5], fmaf(w12, V[m][6], w13 * V[m][7])));
    sp[5] = fmaf(w10, V[m][8], fmaf(w11, V[m][9], fmaf(w12, V[m][10], w13 * V[m][11])));
    sp[6] = fmaf(w10, V[m][12], fmaf(w11, V[m][13], fmaf(w12, V[m][14], w13 * V[m][15])));
    sp[7] = fmaf(w20, V[m][8], fmaf(w21, V[m][9], fmaf(w22, V[m][10], w23 * V[m][11])));
    sp[8] = fmaf(w20, V[m][12], fmaf(w21, V[m][13], fmaf(w22, V[m][14], w23 * V[m][15])));
    sp[9] = fmaf(w30, V[m][12], fmaf(w31, V[m][13], fmaf(w32, V[m][14], w33 * V[m][15])));
  }

  __syncthreads();

  // cooperative coalesced float4 store of this block's [valid*10] floats
  const int valid = min(MPB, B - base);
  const int nf = valid * 10;
  const int n4 = nf >> 2;
  float* obase = out + (size_t)base * 10;
  const float4* s4 = (const float4*)so;
  float4* o4 = (float4*)obase;
  for (int i = t; i < n4; i += BT) o4[i] = s4[i];
  for (int i = n4 * 4 + t; i < nf; i += BT) obase[i] = so[i];
}

extern "C" void kernel_launch(void* const* d_in, const int* in_sizes, int n_in,
                              void* d_out, int out_size, void* d_ws, size_t ws_size,
                              hipStream_t stream) {
  const float* x = (const float*)d_in[0];
  float* out = (float*)d_out;
  const int B = in_sizes[0] / 16;
  const int blocks = (B + MPB - 1) / MPB;
  hipLaunchKernelGGL(TangentSpaceLayer_64141041598486_kernel, dim3(blocks),
                     dim3(BT), 0, stream, x, out, B);
}